// Round 4
// baseline (263.464 us; speedup 1.0000x reference)
//
#include <hip/hip_runtime.h>

#define B_DIM 4
#define L_DIM 4096
#define H_DIM 1024
#define U_DIM 1024
#define M_DIM (B_DIM * L_DIM)   // 16384
#define LC 64                    // scan chunk length
#define NCH (L_DIM / LC)         // 64 chunks per sequence

using f32x4  = __attribute__((ext_vector_type(4))) float;
using bf16x8 = __attribute__((ext_vector_type(8))) __bf16;
using us8    = __attribute__((ext_vector_type(8))) unsigned short;

__device__ inline unsigned short f32_to_bf16(float f) {
  unsigned int u = __float_as_uint(f);
  u += 0x7FFF + ((u >> 16) & 1);   // round-to-nearest-even
  return (unsigned short)(u >> 16);
}
__device__ inline float bf16_to_f32(unsigned short v) {
  return __uint_as_float((unsigned int)v << 16);
}

__device__ inline void async_load16(const void* g, void* l) {
  // gfx950 global->LDS direct, 16B/lane; LDS dest = wave-uniform base + lane*16.
  __builtin_amdgcn_global_load_lds(
      (const __attribute__((address_space(1))) void*)g,
      (__attribute__((address_space(3))) void*)l, 16, 0, 0);
}

// ---------------- fused fp32 -> bf16 convert: inputs, Wi, Wo ----------------
#define IN_ELEMS  (M_DIM * H_DIM)          // 16777216
#define WI_ELEMS  (U_DIM * H_DIM)          // 1048576
#define WO_ELEMS  (H_DIM * U_DIM)          // 1048576
#define CVT_TOTAL (IN_ELEMS + WI_ELEMS + WO_ELEMS)

__global__ __launch_bounds__(256) void cvt_all(
    const float* __restrict__ inp, const float* __restrict__ wi,
    const float* __restrict__ wo,
    unsigned short* __restrict__ inp_b, unsigned short* __restrict__ wi_b,
    unsigned short* __restrict__ wo_b)
{
  size_t e = ((size_t)blockIdx.x * 256 + threadIdx.x) * 8;
  if (e >= CVT_TOTAL) return;
  const float* src; unsigned short* dst; size_t off;
  if (e < IN_ELEMS)                 { src = inp; dst = inp_b; off = e; }
  else if (e < IN_ELEMS + WI_ELEMS) { src = wi;  dst = wi_b;  off = e - IN_ELEMS; }
  else                              { src = wo;  dst = wo_b;  off = e - IN_ELEMS - WI_ELEMS; }
  f32x4 a = *(const f32x4*)(src + off);
  f32x4 b = *(const f32x4*)(src + off + 4);
  us8 r;
  r[0] = f32_to_bf16(a.x); r[1] = f32_to_bf16(a.y);
  r[2] = f32_to_bf16(a.z); r[3] = f32_to_bf16(a.w);
  r[4] = f32_to_bf16(b.x); r[5] = f32_to_bf16(b.y);
  r[6] = f32_to_bf16(b.z); r[7] = f32_to_bf16(b.w);
  *(us8*)(dst + off) = r;
}

// ---------------- GEMM: C[M,N] = A[M,K](bf16) * B[N,K]^T(bf16) + bias[N] ----
// 2-stage software-pipelined K-loop: stage i+1's global_load_lds issued during
// stage i's compute; s_waitcnt vmcnt(4) waits only the OLDER stage (never a
// full drain except last iter). Raw s_barrier — no compiler vmcnt(0).
#define TM 128
#define TN 128
#define BK 32

template <typename OUT>
__global__ __launch_bounds__(256) void gemm_bt_bias(
    const unsigned short* __restrict__ A, const unsigned short* __restrict__ Bm,
    const float* __restrict__ bias, OUT* __restrict__ C,
    int M, int N, int K)
{
  // per stage: 128 rows x 32 bf16 = 64B rows, 8KB; 2 stages x (A+B) = 32KB
  __shared__ __attribute__((aligned(16))) unsigned short sA[2][TM * BK];
  __shared__ __attribute__((aligned(16))) unsigned short sB[2][TN * BK];

  const int tid    = threadIdx.x;
  const int lane   = tid & 63;
  const int wave   = tid >> 6;
  const int wm     = wave & 1;
  const int wn     = wave >> 1;
  const int frag_m = lane & 15;
  const int frag_kb = (lane >> 4) * 16;   // byte offset of 8-bf16 k-group

  // XCD-aware swizzle: dispatch index p -> XCD p%8; each XCD gets a 16-tall
  // M-slab x all N-tiles (A-slab 4MB + B 2MB ~ L2-resident).
  const int p    = blockIdx.y * gridDim.x + blockIdx.x;
  const int xcd  = p & 7;
  const int j    = p >> 3;
  const int slab = gridDim.y >> 3;
  const int by   = xcd * slab + (j % slab);
  const int bx   = j / slab;

  const int m0 = by * TM;
  const int n0 = bx * TN;

  const char* Ab = (const char*)A;
  const char* Bb = (const char*)Bm;
  const size_t rowbytes = (size_t)K * 2;

  // staging geometry: byte offset o in [0,8192); row = o>>6, colbyte = o&63
  const int o0 = tid * 16;          // [0,4096)
  const int o1 = o0 + 4096;         // [4096,8192)
  const int r0s = o0 >> 6, c0s = o0 & 63;
  const int r1s = o1 >> 6, c1s = o1 & 63;

  f32x4 acc[4][4];
  #pragma unroll
  for (int i = 0; i < 4; ++i)
    #pragma unroll
    for (int jj = 0; jj < 4; ++jj)
      acc[i][jj] = {0.f, 0.f, 0.f, 0.f};

  // stage loader: 4 async 16B/lane loads (counted by vmcnt)
  auto stage = [&](int s, int kk) {
    const size_t kb = (size_t)kk * 2;
    async_load16(Ab + (size_t)(m0 + r0s) * rowbytes + kb + c0s, (char*)sA[s] + o0);
    async_load16(Ab + (size_t)(m0 + r1s) * rowbytes + kb + c1s, (char*)sA[s] + o1);
    async_load16(Bb + (size_t)(n0 + r0s) * rowbytes + kb + c0s, (char*)sB[s] + o0);
    async_load16(Bb + (size_t)(n0 + r1s) * rowbytes + kb + c1s, (char*)sB[s] + o1);
  };

  const int NI = K / BK;
  stage(0, 0);

  for (int i = 0; i < NI; ++i) {
    if (i + 1 < NI) {
      stage((i + 1) & 1, (i + 1) * BK);             // 8 outstanding now
      // wait the OLDER 4 (stage i) only; stage i+1 stays in flight
      asm volatile("s_waitcnt vmcnt(4)\n\ts_barrier" ::: "memory");
    } else {
      asm volatile("s_waitcnt vmcnt(0)\n\ts_barrier" ::: "memory");
    }

    const int s = i & 1;
    bf16x8 af[4], bf[4];
    #pragma unroll
    for (int mi = 0; mi < 4; ++mi)
      af[mi] = *(const bf16x8*)((const char*)sA[s] + (wm * 64 + mi * 16 + frag_m) * 64 + frag_kb);
    #pragma unroll
    for (int ni = 0; ni < 4; ++ni)
      bf[ni] = *(const bf16x8*)((const char*)sB[s] + (wn * 64 + ni * 16 + frag_m) * 64 + frag_kb);

    #pragma unroll
    for (int mi = 0; mi < 4; ++mi)
      #pragma unroll
      for (int ni = 0; ni < 4; ++ni)
        acc[mi][ni] = __builtin_amdgcn_mfma_f32_16x16x32_bf16(af[mi], bf[ni], acc[mi][ni], 0, 0, 0);

    // all waves done reading buf s before iter i+1 overwrites it
    asm volatile("s_barrier" ::: "memory");
  }

  // Epilogue: D row = (lane>>4)*4 + r, col = lane&15  [m89-verified layout]
  const int rr0 = (lane >> 4) * 4;
  #pragma unroll
  for (int ni = 0; ni < 4; ++ni) {
    int col  = n0 + wn * 64 + ni * 16 + frag_m;
    float bv = bias[col];
    #pragma unroll
    for (int mi = 0; mi < 4; ++mi) {
      int rowb = m0 + wm * 64 + mi * 16 + rr0;
      #pragma unroll
      for (int r = 0; r < 4; ++r) {
        float v = acc[mi][ni][r] + bv;
        if constexpr (sizeof(OUT) == 2)
          C[(size_t)(rowb + r) * N + col] = (OUT)f32_to_bf16(v);
        else
          C[(size_t)(rowb + r) * N + col] = (OUT)v;
      }
    }
  }
}

// ---------------- scan phase A: per-chunk local carry (bf16 u) ---------------
__global__ __launch_bounds__(256) void scan_carry(
    const unsigned short* __restrict__ u, const float* __restrict__ params_log,
    float* __restrict__ carry)
{
  int uu = blockIdx.x * 256 + threadIdx.x;
  int c  = blockIdx.y;
  int b  = blockIdx.z;
  float l = expf(-expf(params_log[uu]));
  const unsigned short* p = u + (size_t)(b * L_DIM + c * LC) * U_DIM + uu;
  float s = 0.f;
  #pragma unroll 8
  for (int j = 0; j < LC; ++j)
    s = fmaf(s, l, bf16_to_f32(p[(size_t)j * U_DIM]));
  carry[((size_t)b * NCH + c) * U_DIM + uu] = s;
}

// ---------------- scan phase B+C fused: inline lookback prefix, apply, bf16 --
__global__ __launch_bounds__(256) void scan_fixup(
    const unsigned short* __restrict__ u, const float* __restrict__ params_log,
    const float* __restrict__ carry, unsigned short* __restrict__ x_b)
{
  int uu = blockIdx.x * 256 + threadIdx.x;
  int c  = blockIdx.y;           // uniform per block -> no divergence
  int b  = blockIdx.z;
  float nu = expf(params_log[uu]);
  float l  = expf(-nu);
  float g  = expf(params_log[U_DIM + uu]);
  float lp = expf(-nu * (float)LC);

  // prefix_c = Horner over carries 0..c-1 (1MB buffer -> L2-resident re-reads)
  const float* cp = carry + (size_t)b * NCH * U_DIM + uu;
  float s = 0.f;
  for (int cc = 0; cc < c; ++cc)
    s = fmaf(s, lp, cp[(size_t)cc * U_DIM]);

  const unsigned short* p = u + (size_t)(b * L_DIM + c * LC) * U_DIM + uu;
  unsigned short* q = x_b + (size_t)(b * L_DIM + c * LC) * U_DIM + uu;
  #pragma unroll 8
  for (int j = 0; j < LC; ++j) {
    s = fmaf(s, l, bf16_to_f32(p[(size_t)j * U_DIM]));
    q[(size_t)j * U_DIM] = f32_to_bf16(s * g);
  }
}

extern "C" void kernel_launch(void* const* d_in, const int* in_sizes, int n_in,
                              void* d_out, int out_size, void* d_ws, size_t ws_size,
                              hipStream_t stream)
{
  const float* inputs     = (const float*)d_in[0];   // (B, L, H)
  const float* Wi         = (const float*)d_in[1];   // (U, H)
  const float* bi         = (const float*)d_in[2];   // (U,)
  const float* Wo         = (const float*)d_in[3];   // (H, U)
  const float* bo         = (const float*)d_in[4];   // (H,)
  const float* params_log = (const float*)d_in[5];   // (2, U)
  float* out = (float*)d_out;                        // (B, L, H) fp32

  char* ws = (char*)d_ws;
  unsigned short* u_b    = (unsigned short*)(ws);                 // 32 MB bf16 u
  unsigned short* x_b    = (unsigned short*)(ws + (32u << 20));   // 32 MB bf16 x
  unsigned short* in_b   = (unsigned short*)(ws + (64u << 20));   // 32 MB bf16 inputs
  unsigned short* wi_b   = (unsigned short*)(ws + (96u << 20));   //  2 MB bf16 Wi
  unsigned short* wo_b   = (unsigned short*)(ws + (98u << 20));   //  2 MB bf16 Wo
  float*          carry  = (float*)(ws + (100u << 20));           //  1 MB

  cvt_all<<<dim3((CVT_TOTAL / 8 + 255) / 256), 256, 0, stream>>>(
      inputs, Wi, Wo, in_b, wi_b, wo_b);

  // GEMM1: u = inputs @ Wi^T + bi   (M=16384, N=U, K=H) -> bf16
  gemm_bt_bias<unsigned short><<<dim3(U_DIM / TN, M_DIM / TM), 256, 0, stream>>>(
      in_b, wi_b, bi, u_b, M_DIM, U_DIM, H_DIM);

  scan_carry<<<dim3(U_DIM / 256, NCH, B_DIM), 256, 0, stream>>>(u_b, params_log, carry);
  scan_fixup<<<dim3(U_DIM / 256, NCH, B_DIM), 256, 0, stream>>>(u_b, params_log, carry, x_b);

  // GEMM2: out = x @ Wo^T + bo   (M=16384, N=H, K=U) -> fp32
  gemm_bt_bias<float><<<dim3(H_DIM / TN, M_DIM / TM), 256, 0, stream>>>(
      x_b, wo_b, bo, out, M_DIM, H_DIM, U_DIM);
}

// Round 5
// 253.606 us; speedup vs baseline: 1.0389x; 1.0389x over previous
//
#include <hip/hip_runtime.h>

#define B_DIM 4
#define L_DIM 4096
#define H_DIM 1024
#define U_DIM 1024
#define M_DIM (B_DIM * L_DIM)   // 16384
#define LC 64                    // scan chunk length
#define NCH (L_DIM / LC)         // 64 chunks per sequence

using f32x4  = __attribute__((ext_vector_type(4))) float;
using bf16x8 = __attribute__((ext_vector_type(8))) __bf16;
using us8    = __attribute__((ext_vector_type(8))) unsigned short;

__device__ inline unsigned short f32_to_bf16(float f) {
  unsigned int u = __float_as_uint(f);
  u += 0x7FFF + ((u >> 16) & 1);   // round-to-nearest-even
  return (unsigned short)(u >> 16);
}
__device__ inline float bf16_to_f32(unsigned short v) {
  return __uint_as_float((unsigned int)v << 16);
}

__device__ inline void async_load16(const void* g, void* l) {
  // gfx950 global->LDS direct, 16B/lane; LDS dest = wave-uniform base + lane*16.
  __builtin_amdgcn_global_load_lds(
      (const __attribute__((address_space(1))) void*)g,
      (__attribute__((address_space(3))) void*)l, 16, 0, 0);
}

// ---------------- fused fp32 -> bf16 convert: inputs, Wi, Wo ----------------
#define IN_ELEMS  (M_DIM * H_DIM)          // 16777216
#define WI_ELEMS  (U_DIM * H_DIM)          // 1048576
#define WO_ELEMS  (H_DIM * U_DIM)          // 1048576
#define CVT_TOTAL (IN_ELEMS + WI_ELEMS + WO_ELEMS)

__global__ __launch_bounds__(256) void cvt_all(
    const float* __restrict__ inp, const float* __restrict__ wi,
    const float* __restrict__ wo,
    unsigned short* __restrict__ inp_b, unsigned short* __restrict__ wi_b,
    unsigned short* __restrict__ wo_b)
{
  size_t e = ((size_t)blockIdx.x * 256 + threadIdx.x) * 8;
  if (e >= CVT_TOTAL) return;
  const float* src; unsigned short* dst; size_t off;
  if (e < IN_ELEMS)                 { src = inp; dst = inp_b; off = e; }
  else if (e < IN_ELEMS + WI_ELEMS) { src = wi;  dst = wi_b;  off = e - IN_ELEMS; }
  else                              { src = wo;  dst = wo_b;  off = e - IN_ELEMS - WI_ELEMS; }
  f32x4 a = *(const f32x4*)(src + off);
  f32x4 b = *(const f32x4*)(src + off + 4);
  us8 r;
  r[0] = f32_to_bf16(a.x); r[1] = f32_to_bf16(a.y);
  r[2] = f32_to_bf16(a.z); r[3] = f32_to_bf16(a.w);
  r[4] = f32_to_bf16(b.x); r[5] = f32_to_bf16(b.y);
  r[6] = f32_to_bf16(b.z); r[7] = f32_to_bf16(b.w);
  *(us8*)(dst + off) = r;
}

// ---------------- GEMM: C[M,N] = A[M,K](bf16) * B[N,K]^T(bf16) + bias[N] ----
// 2-stage pipelined K-loop + XOR bank-swizzle on LDS k-groups:
//   LDS row r position p holds global k-group (p ^ ((r>>1)&3)).
//   Store side (global_load_lds): permute per-lane GLOBAL address (same 64B
//   line per row -> coalescing unchanged). Read side: bank-quad =
//   4(i&1) + (q ^ ((i>>1)&3)) -> only the free 2-way aliasing.
// GEMM1 additionally computes per-chunk scan carries from the accumulators
// (carry_c = sum_j lam^(63-j) u_j, a weighted sum: lane partials + shfl_xor).
#define TM 128
#define TN 128
#define BK 32

template <typename OUT, bool CARRY, int K>
__global__ __launch_bounds__(256) void gemm_bt_bias(
    const unsigned short* __restrict__ A, const unsigned short* __restrict__ Bm,
    const float* __restrict__ bias, OUT* __restrict__ C,
    int M, int N,
    float* __restrict__ carry_out, const float* __restrict__ params_log)
{
  __shared__ __attribute__((aligned(16))) unsigned short sA[2][TM * BK];
  __shared__ __attribute__((aligned(16))) unsigned short sB[2][TN * BK];

  const int tid    = threadIdx.x;
  const int lane   = tid & 63;
  const int wave   = tid >> 6;
  const int wm     = wave & 1;
  const int wn     = wave >> 1;
  const int frag_m = lane & 15;
  const int quad   = lane >> 4;
  // swizzled byte offset of this lane's 8-bf16 k-group within a 64B row
  const int frag_kb = 16 * (quad ^ ((lane >> 1) & 3));

  // XCD-aware swizzle: dispatch p -> XCD p%8; each XCD gets a 16-tall M-slab
  // x all N-tiles (A-slab 4MB + B 2MB ~ L2-resident).
  const int p    = blockIdx.y * gridDim.x + blockIdx.x;
  const int xcd  = p & 7;
  const int j    = p >> 3;
  const int slab = gridDim.y >> 3;
  const int by   = xcd * slab + (j % slab);
  const int bx   = j / slab;

  const int m0 = by * TM;
  const int n0 = bx * TN;

  const char* Ab = (const char*)A;
  const char* Bb = (const char*)Bm;
  const size_t rowbytes = (size_t)K * 2;

  // staging: thread covers LDS offsets tid*16 and tid*16+4096
  //   row0 = tid>>2, row1 = 64+row0, LDS position = tid&3
  //   global k-group fetched = (tid&3) ^ sigma(row), sigma(row)=(row>>1)&3 -> (tid>>3)&3
  const int r0s  = tid >> 2;
  const int r1s  = r0s + 64;
  const int csw  = 16 * ((tid & 3) ^ ((tid >> 3) & 3));
  const int o0   = tid * 16;
  const int o1   = o0 + 4096;

  f32x4 acc[4][4];
  #pragma unroll
  for (int i = 0; i < 4; ++i)
    #pragma unroll
    for (int jj = 0; jj < 4; ++jj)
      acc[i][jj] = {0.f, 0.f, 0.f, 0.f};

  auto stage = [&](int s, int kk) {
    const size_t kb = (size_t)kk * 2;
    async_load16(Ab + (size_t)(m0 + r0s) * rowbytes + kb + csw, (char*)sA[s] + o0);
    async_load16(Ab + (size_t)(m0 + r1s) * rowbytes + kb + csw, (char*)sA[s] + o1);
    async_load16(Bb + (size_t)(n0 + r0s) * rowbytes + kb + csw, (char*)sB[s] + o0);
    async_load16(Bb + (size_t)(n0 + r1s) * rowbytes + kb + csw, (char*)sB[s] + o1);
  };

  constexpr int NI = K / BK;
  stage(0, 0);

  #pragma unroll 2
  for (int i = 0; i < NI; ++i) {
    if (i + 1 < NI) {
      stage((i + 1) & 1, (i + 1) * BK);
      asm volatile("s_waitcnt vmcnt(4)\n\ts_barrier" ::: "memory");
    } else {
      asm volatile("s_waitcnt vmcnt(0)\n\ts_barrier" ::: "memory");
    }

    const int s = i & 1;
    bf16x8 af[4], bf[4];
    #pragma unroll
    for (int mi = 0; mi < 4; ++mi)
      af[mi] = *(const bf16x8*)((const char*)sA[s] + (wm * 64 + mi * 16 + frag_m) * 64 + frag_kb);
    #pragma unroll
    for (int ni = 0; ni < 4; ++ni)
      bf[ni] = *(const bf16x8*)((const char*)sB[s] + (wn * 64 + ni * 16 + frag_m) * 64 + frag_kb);

    #pragma unroll
    for (int mi = 0; mi < 4; ++mi)
      #pragma unroll
      for (int ni = 0; ni < 4; ++ni)
        acc[mi][ni] = __builtin_amdgcn_mfma_f32_16x16x32_bf16(af[mi], bf[ni], acc[mi][ni], 0, 0, 0);

    asm volatile("s_barrier" ::: "memory");
  }

  // Epilogue: D row = quad*4 + r, col = lane&15  [m89-verified layout]
  const int rr0 = quad * 4;
  #pragma unroll
  for (int ni = 0; ni < 4; ++ni) {
    int col  = n0 + wn * 64 + ni * 16 + frag_m;
    float bv = bias[col];
    #pragma unroll
    for (int mi = 0; mi < 4; ++mi) {
      int rowb = m0 + wm * 64 + mi * 16 + rr0;
      #pragma unroll
      for (int r = 0; r < 4; ++r) {
        float v = acc[mi][ni][r] + bv;
        if constexpr (sizeof(OUT) == 2)
          C[(size_t)(rowb + r) * N + col] = (OUT)f32_to_bf16(v);
        else
          C[(size_t)(rowb + r) * N + col] = (OUT)v;
      }
    }
  }

  if constexpr (CARRY) {
    // Wave wm's 64 rows are exactly chunk (m0>>6)+wm (since NCH*LC == L and
    // M-rows are (b,l) flattened). carry = sum_j lam^(63-j) * u_j.
    const int chunk = (m0 >> 6) + wm;      // == b*NCH + c
    #pragma unroll
    for (int ni = 0; ni < 4; ++ni) {
      int col  = n0 + wn * 64 + ni * 16 + frag_m;
      float bv = bias[col];
      float nu = expf(params_log[col]);
      float w_base = expf(-nu * (float)(63 - quad * 4));  // lam^(63-quad*4)
      float linv   = expf(nu);          // lam^-1
      float l16inv = expf(16.f * nu);   // lam^-16
      float part = 0.f;
      float wmi  = w_base;
      #pragma unroll
      for (int mi = 0; mi < 4; ++mi) {
        float w = wmi;
        #pragma unroll
        for (int r = 0; r < 4; ++r) {
          part = fmaf(w, acc[mi][ni][r] + bv, part);
          w *= linv;
        }
        wmi *= l16inv;
      }
      part += __shfl_xor(part, 16);
      part += __shfl_xor(part, 32);
      if (quad == 0)
        carry_out[(size_t)chunk * U_DIM + col] = part;
    }
  }
}

// ---------------- scan phase B: prefix over chunk carries (batched loads) ----
__global__ __launch_bounds__(256) void scan_prefix(
    const float* __restrict__ carry, const float* __restrict__ params_log,
    float* __restrict__ prefix)
{
  int t  = blockIdx.x * 256 + threadIdx.x;   // over B*U
  int b  = t >> 10;
  int uu = t & (U_DIM - 1);
  float lp = expf(-expf(params_log[uu]) * (float)LC);
  const float* cp = carry  + (size_t)b * NCH * U_DIM + uu;
  float*       pp = prefix + (size_t)b * NCH * U_DIM + uu;
  float vals[NCH];
  #pragma unroll
  for (int c = 0; c < NCH; ++c)
    vals[c] = cp[(size_t)c * U_DIM];          // independent, all in flight
  float s = 0.f;
  #pragma unroll
  for (int c = 0; c < NCH; ++c) {
    pp[(size_t)c * U_DIM] = s;
    s = fmaf(s, lp, vals[c]);
  }
}

// ---------------- scan phase C: local scan + carry-in, *gamma, bf16 out ------
__global__ __launch_bounds__(256) void scan_apply(
    const unsigned short* __restrict__ u, const float* __restrict__ params_log,
    const float* __restrict__ prefix, unsigned short* __restrict__ x_b)
{
  int uu = blockIdx.x * 256 + threadIdx.x;
  int c  = blockIdx.y;
  int b  = blockIdx.z;
  float l = expf(-expf(params_log[uu]));
  float g = expf(params_log[U_DIM + uu]);
  float s = prefix[((size_t)b * NCH + c) * U_DIM + uu];
  const unsigned short* p = u + (size_t)(b * L_DIM + c * LC) * U_DIM + uu;
  unsigned short* q = x_b + (size_t)(b * L_DIM + c * LC) * U_DIM + uu;
  #pragma unroll 8
  for (int j = 0; j < LC; ++j) {
    s = fmaf(s, l, bf16_to_f32(p[(size_t)j * U_DIM]));
    q[(size_t)j * U_DIM] = f32_to_bf16(s * g);
  }
}

extern "C" void kernel_launch(void* const* d_in, const int* in_sizes, int n_in,
                              void* d_out, int out_size, void* d_ws, size_t ws_size,
                              hipStream_t stream)
{
  const float* inputs     = (const float*)d_in[0];   // (B, L, H)
  const float* Wi         = (const float*)d_in[1];   // (U, H)
  const float* bi         = (const float*)d_in[2];   // (U,)
  const float* Wo         = (const float*)d_in[3];   // (H, U)
  const float* bo         = (const float*)d_in[4];   // (H,)
  const float* params_log = (const float*)d_in[5];   // (2, U)
  float* out = (float*)d_out;                        // (B, L, H) fp32

  char* ws = (char*)d_ws;
  unsigned short* u_b    = (unsigned short*)(ws);                 // 32 MB bf16 u
  unsigned short* x_b    = (unsigned short*)(ws + (32u << 20));   // 32 MB bf16 x
  unsigned short* in_b   = (unsigned short*)(ws + (64u << 20));   // 32 MB bf16 inputs
  unsigned short* wi_b   = (unsigned short*)(ws + (96u << 20));   //  2 MB bf16 Wi
  unsigned short* wo_b   = (unsigned short*)(ws + (98u << 20));   //  2 MB bf16 Wo
  float*          carry  = (float*)(ws + (100u << 20));           //  1 MB
  float*          prefix = (float*)(ws + (101u << 20));           //  1 MB

  cvt_all<<<dim3((CVT_TOTAL / 8 + 255) / 256), 256, 0, stream>>>(
      inputs, Wi, Wo, in_b, wi_b, wo_b);

  // GEMM1: u = inputs @ Wi^T + bi  (M=16384, N=U, K=H) -> bf16 u + chunk carries
  gemm_bt_bias<unsigned short, true, H_DIM>
      <<<dim3(U_DIM / TN, M_DIM / TM), 256, 0, stream>>>(
      in_b, wi_b, bi, u_b, M_DIM, U_DIM, carry, params_log);

  scan_prefix<<<dim3(B_DIM * U_DIM / 256),     256, 0, stream>>>(carry, params_log, prefix);
  scan_apply <<<dim3(U_DIM / 256, NCH, B_DIM), 256, 0, stream>>>(u_b, params_log, prefix, x_b);

  // GEMM2: out = x @ Wo^T + bo   (M=16384, N=H, K=U) -> fp32
  gemm_bt_bias<float, false, U_DIM>
      <<<dim3(H_DIM / TN, M_DIM / TM), 256, 0, stream>>>(
      x_b, wo_b, bo, out, M_DIM, H_DIM, nullptr, nullptr);
}

// Round 6
// 253.191 us; speedup vs baseline: 1.0406x; 1.0016x over previous
//
#include <hip/hip_runtime.h>

#define B_DIM 4
#define L_DIM 4096
#define H_DIM 1024
#define U_DIM 1024
#define M_DIM (B_DIM * L_DIM)   // 16384
#define LC 64                    // scan chunk length
#define NCH (L_DIM / LC)         // 64 chunks per sequence

using f32x4  = __attribute__((ext_vector_type(4))) float;
using bf16x8 = __attribute__((ext_vector_type(8))) __bf16;
using us8    = __attribute__((ext_vector_type(8))) unsigned short;

__device__ inline unsigned short f32_to_bf16(float f) {
  unsigned int u = __float_as_uint(f);
  u += 0x7FFF + ((u >> 16) & 1);   // round-to-nearest-even
  return (unsigned short)(u >> 16);
}
__device__ inline float bf16_to_f32(unsigned short v) {
  return __uint_as_float((unsigned int)v << 16);
}

// ---------------- fused fp32 -> bf16 convert: inputs, Wi, Wo ----------------
#define IN_ELEMS  (M_DIM * H_DIM)          // 16777216
#define WI_ELEMS  (U_DIM * H_DIM)          // 1048576
#define WO_ELEMS  (H_DIM * U_DIM)          // 1048576
#define CVT_TOTAL (IN_ELEMS + WI_ELEMS + WO_ELEMS)

__global__ __launch_bounds__(256) void cvt_all(
    const float* __restrict__ inp, const float* __restrict__ wi,
    const float* __restrict__ wo,
    unsigned short* __restrict__ inp_b, unsigned short* __restrict__ wi_b,
    unsigned short* __restrict__ wo_b)
{
  size_t e = ((size_t)blockIdx.x * 256 + threadIdx.x) * 8;
  if (e >= CVT_TOTAL) return;
  const float* src; unsigned short* dst; size_t off;
  if (e < IN_ELEMS)                 { src = inp; dst = inp_b; off = e; }
  else if (e < IN_ELEMS + WI_ELEMS) { src = wi;  dst = wi_b;  off = e - IN_ELEMS; }
  else                              { src = wo;  dst = wo_b;  off = e - IN_ELEMS - WI_ELEMS; }
  f32x4 a = *(const f32x4*)(src + off);
  f32x4 b = *(const f32x4*)(src + off + 4);
  us8 r;
  r[0] = f32_to_bf16(a.x); r[1] = f32_to_bf16(a.y);
  r[2] = f32_to_bf16(a.z); r[3] = f32_to_bf16(a.w);
  r[4] = f32_to_bf16(b.x); r[5] = f32_to_bf16(b.y);
  r[6] = f32_to_bf16(b.z); r[7] = f32_to_bf16(b.w);
  *(us8*)(dst + off) = r;
}

// ---------------- GEMM: C[M,N] = A[M,K](bf16) * B[N,K]^T(bf16) + bias[N] ----
// hipBLASLt-shaped pipeline: buffer_load(i+1)->VGPR issued BEFORE iter i's
// MFMAs; ds_write after MFMAs (compiler's vmcnt wait lands post-compute, so
// loads are resident -> no drain stall); ONE barrier per iter.
// LDS-side XOR swizzle: row r, k-group c stored at byte 16*(c ^ ((r>>1)&3)) ->
// global loads identity-coalesced AND LDS reads/writes conflict-free
// (round-5 measured SQ_LDS_BANK_CONFLICT = 0 with this read pattern).
// GEMM1 additionally computes per-chunk scan carries from the accumulators.
#define TM 128
#define TN 128
#define BK 32

template <typename OUT, bool CARRY, int K>
__global__ __launch_bounds__(256) void gemm_bt_bias(
    const unsigned short* __restrict__ A, const unsigned short* __restrict__ Bm,
    const float* __restrict__ bias, OUT* __restrict__ C,
    int M, int N,
    float* __restrict__ carry_out, const float* __restrict__ params_log)
{
  __shared__ __attribute__((aligned(16))) unsigned short sA[2][TM * BK];
  __shared__ __attribute__((aligned(16))) unsigned short sB[2][TN * BK];

  const int tid    = threadIdx.x;
  const int lane   = tid & 63;
  const int wave   = tid >> 6;
  const int wm     = wave & 1;
  const int wn     = wave >> 1;
  const int frag_m = lane & 15;
  const int quad   = lane >> 4;
  // swizzled read offset: row's sigma = (row>>1)&3 reduces to (lane>>1)&3
  // (mi*16 and wm*64 contribute 0 mod 4 after >>1)
  const int frag_kb = 16 * (quad ^ ((lane >> 1) & 3));

  // XCD-aware swizzle: dispatch p -> XCD p%8; each XCD gets a 16-tall M-slab
  // x all N-tiles (A-slab 4MB + B 2MB ~ L2-resident).
  const int p    = blockIdx.y * gridDim.x + blockIdx.x;
  const int xcd  = p & 7;
  const int j    = p >> 3;
  const int slab = gridDim.y >> 3;
  const int by   = xcd * slab + (j % slab);
  const int bx   = j / slab;

  const int m0 = by * TM;
  const int n0 = bx * TN;

  const char* Ab = (const char*)A;
  const char* Bb = (const char*)Bm;
  const size_t rowbytes = (size_t)K * 2;

  // staging: thread covers rows r0=tid>>2 and r1=r0+64, k-group cg=tid&3.
  // global: identity (row-major, 16B at byte cg*16 of the 64B k-slice)
  // LDS: row*64 + 16*(cg ^ ((row>>1)&3));  r1 has same sigma -> lo1 = lo0+4096
  const int r0s = tid >> 2;
  const int r1s = r0s + 64;
  const int cg  = tid & 3;
  const int lo0 = r0s * 64 + 16 * (cg ^ ((tid >> 3) & 3));
  const int lo1 = lo0 + 4096;

  f32x4 acc[4][4];
  #pragma unroll
  for (int i = 0; i < 4; ++i)
    #pragma unroll
    for (int jj = 0; jj < 4; ++jj)
      acc[i][jj] = {0.f, 0.f, 0.f, 0.f};

  us8 pa0, pa1, pb0, pb1;   // prefetch registers
  auto gload = [&](int kk) {
    const size_t kb = (size_t)kk * 2 + cg * 16;
    pa0 = *(const us8*)(Ab + (size_t)(m0 + r0s) * rowbytes + kb);
    pa1 = *(const us8*)(Ab + (size_t)(m0 + r1s) * rowbytes + kb);
    pb0 = *(const us8*)(Bb + (size_t)(n0 + r0s) * rowbytes + kb);
    pb1 = *(const us8*)(Bb + (size_t)(n0 + r1s) * rowbytes + kb);
  };
  auto swrite = [&](int s) {
    *(us8*)((char*)sA[s] + lo0) = pa0;
    *(us8*)((char*)sA[s] + lo1) = pa1;
    *(us8*)((char*)sB[s] + lo0) = pb0;
    *(us8*)((char*)sB[s] + lo1) = pb1;
  };

  constexpr int NI = K / BK;
  gload(0);
  swrite(0);
  __syncthreads();

  for (int i = 0; i < NI; ++i) {
    if (i + 1 < NI)
      gload((i + 1) * BK);            // in flight across the whole MFMA phase

    const int s = i & 1;
    bf16x8 af[4], bf[4];
    #pragma unroll
    for (int mi = 0; mi < 4; ++mi)
      af[mi] = *(const bf16x8*)((const char*)sA[s] + (wm * 64 + mi * 16 + frag_m) * 64 + frag_kb);
    #pragma unroll
    for (int ni = 0; ni < 4; ++ni)
      bf[ni] = *(const bf16x8*)((const char*)sB[s] + (wn * 64 + ni * 16 + frag_m) * 64 + frag_kb);

    #pragma unroll
    for (int mi = 0; mi < 4; ++mi)
      #pragma unroll
      for (int ni = 0; ni < 4; ++ni)
        acc[mi][ni] = __builtin_amdgcn_mfma_f32_16x16x32_bf16(af[mi], bf[ni], acc[mi][ni], 0, 0, 0);

    if (i + 1 < NI) {
      swrite((i + 1) & 1);            // vmcnt wait lands here, post-compute
      __syncthreads();                // separates writes(i+1) from reads(i+1);
                                      // reads(i) already consumed by MFMA issue
    }
  }

  // Epilogue: D row = quad*4 + r, col = lane&15  [m89-verified layout]
  const int rr0 = quad * 4;
  #pragma unroll
  for (int ni = 0; ni < 4; ++ni) {
    int col  = n0 + wn * 64 + ni * 16 + frag_m;
    float bv = bias[col];
    #pragma unroll
    for (int mi = 0; mi < 4; ++mi) {
      int rowb = m0 + wm * 64 + mi * 16 + rr0;
      #pragma unroll
      for (int r = 0; r < 4; ++r) {
        float v = acc[mi][ni][r] + bv;
        if constexpr (sizeof(OUT) == 2)
          C[(size_t)(rowb + r) * N + col] = (OUT)f32_to_bf16(v);
        else
          C[(size_t)(rowb + r) * N + col] = (OUT)v;
      }
    }
  }

  if constexpr (CARRY) {
    // Wave wm's 64 rows form exactly chunk (m0>>6)+wm. carry = sum_j lam^(63-j) u_j.
    const int chunk = (m0 >> 6) + wm;      // == b*NCH + c
    #pragma unroll
    for (int ni = 0; ni < 4; ++ni) {
      int col  = n0 + wn * 64 + ni * 16 + frag_m;
      float bv = bias[col];
      float nu = expf(params_log[col]);
      float w_base = expf(-nu * (float)(63 - quad * 4));  // lam^(63-quad*4)
      float linv   = expf(nu);          // lam^-1
      float l16inv = expf(16.f * nu);   // lam^-16
      float part = 0.f;
      float wmi  = w_base;
      #pragma unroll
      for (int mi = 0; mi < 4; ++mi) {
        float w = wmi;
        #pragma unroll
        for (int r = 0; r < 4; ++r) {
          part = fmaf(w, acc[mi][ni][r] + bv, part);
          w *= linv;
        }
        wmi *= l16inv;
      }
      part += __shfl_xor(part, 16);
      part += __shfl_xor(part, 32);
      if (quad == 0)
        carry_out[(size_t)chunk * U_DIM + col] = part;
    }
  }
}

// ---------------- scan phase B: prefix over chunk carries (batched loads) ----
__global__ __launch_bounds__(256) void scan_prefix(
    const float* __restrict__ carry, const float* __restrict__ params_log,
    float* __restrict__ prefix)
{
  int t  = blockIdx.x * 256 + threadIdx.x;   // over B*U
  int b  = t >> 10;
  int uu = t & (U_DIM - 1);
  float lp = expf(-expf(params_log[uu]) * (float)LC);
  const float* cp = carry  + (size_t)b * NCH * U_DIM + uu;
  float*       pp = prefix + (size_t)b * NCH * U_DIM + uu;
  float vals[NCH];
  #pragma unroll
  for (int c = 0; c < NCH; ++c)
    vals[c] = cp[(size_t)c * U_DIM];          // independent, all in flight
  float s = 0.f;
  #pragma unroll
  for (int c = 0; c < NCH; ++c) {
    pp[(size_t)c * U_DIM] = s;
    s = fmaf(s, lp, vals[c]);
  }
}

// ---------------- scan phase C: local scan + carry-in, *gamma, bf16 out ------
__global__ __launch_bounds__(256) void scan_apply(
    const unsigned short* __restrict__ u, const float* __restrict__ params_log,
    const float* __restrict__ prefix, unsigned short* __restrict__ x_b)
{
  int uu = blockIdx.x * 256 + threadIdx.x;
  int c  = blockIdx.y;
  int b  = blockIdx.z;
  float l = expf(-expf(params_log[uu]));
  float g = expf(params_log[U_DIM + uu]);
  float s = prefix[((size_t)b * NCH + c) * U_DIM + uu];
  const unsigned short* p = u + (size_t)(b * L_DIM + c * LC) * U_DIM + uu;
  unsigned short* q = x_b + (size_t)(b * L_DIM + c * LC) * U_DIM + uu;
  #pragma unroll 8
  for (int j = 0; j < LC; ++j) {
    s = fmaf(s, l, bf16_to_f32(p[(size_t)j * U_DIM]));
    q[(size_t)j * U_DIM] = f32_to_bf16(s * g);
  }
}

extern "C" void kernel_launch(void* const* d_in, const int* in_sizes, int n_in,
                              void* d_out, int out_size, void* d_ws, size_t ws_size,
                              hipStream_t stream)
{
  const float* inputs     = (const float*)d_in[0];   // (B, L, H)
  const float* Wi         = (const float*)d_in[1];   // (U, H)
  const float* bi         = (const float*)d_in[2];   // (U,)
  const float* Wo         = (const float*)d_in[3];   // (H, U)
  const float* bo         = (const float*)d_in[4];   // (H,)
  const float* params_log = (const float*)d_in[5];   // (2, U)
  float* out = (float*)d_out;                        // (B, L, H) fp32

  char* ws = (char*)d_ws;
  unsigned short* u_b    = (unsigned short*)(ws);                 // 32 MB bf16 u
  unsigned short* x_b    = (unsigned short*)(ws + (32u << 20));   // 32 MB bf16 x
  unsigned short* in_b   = (unsigned short*)(ws + (64u << 20));   // 32 MB bf16 inputs
  unsigned short* wi_b   = (unsigned short*)(ws + (96u << 20));   //  2 MB bf16 Wi
  unsigned short* wo_b   = (unsigned short*)(ws + (98u << 20));   //  2 MB bf16 Wo
  float*          carry  = (float*)(ws + (100u << 20));           //  1 MB
  float*          prefix = (float*)(ws + (101u << 20));           //  1 MB

  cvt_all<<<dim3((CVT_TOTAL / 8 + 255) / 256), 256, 0, stream>>>(
      inputs, Wi, Wo, in_b, wi_b, wo_b);

  // GEMM1: u = inputs @ Wi^T + bi  (M=16384, N=U, K=H) -> bf16 u + chunk carries
  gemm_bt_bias<unsigned short, true, H_DIM>
      <<<dim3(U_DIM / TN, M_DIM / TM), 256, 0, stream>>>(
      in_b, wi_b, bi, u_b, M_DIM, U_DIM, carry, params_log);

  scan_prefix<<<dim3(B_DIM * U_DIM / 256),     256, 0, stream>>>(carry, params_log, prefix);
  scan_apply <<<dim3(U_DIM / 256, NCH, B_DIM), 256, 0, stream>>>(u_b, params_log, prefix, x_b);

  // GEMM2: out = x @ Wo^T + bo   (M=16384, N=H, K=U) -> fp32
  gemm_bt_bias<float, false, U_DIM>
      <<<dim3(H_DIM / TN, M_DIM / TM), 256, 0, stream>>>(
      x_b, wo_b, bo, out, M_DIM, H_DIM, nullptr, nullptr);
}